// Round 9
// baseline (12353.458 us; speedup 1.0000x reference)
//
#include <hip/hip_runtime.h>
#include <math.h>

#define B_   32
#define L_   197
#define E_   384
#define DI_  768
#define DS_  16
#define DR_  24
#define NP_  196
#define ROWS (B_ * L_)         // 6304
#define OUT0 (ROWS * E_)       // 2420736
#define FEAT (B_ * E_ * NP_)   // 2408448

typedef __attribute__((ext_vector_type(8))) short bf16x8;
typedef __attribute__((ext_vector_type(4))) float f32x4;

__device__ __forceinline__ float silu_f(float x) { return x / (1.f + __expf(-x)); }

__device__ __forceinline__ unsigned short f2bf(float x) {
    unsigned int u = __float_as_uint(x);
    u += 0x7fffu + ((u >> 16) & 1u);
    return (unsigned short)(u >> 16);
}
__device__ __forceinline__ float bf2f(unsigned short u) {
    return __uint_as_float((unsigned int)u << 16);
}

// ---------------- im2col for patch embedding ----------------
__global__ __launch_bounds__(256) void im2col_kernel(const float* __restrict__ x,
                                                     float* __restrict__ xcol) {
    int idx = blockIdx.x * 256 + threadIdx.x;
    if (idx >= B_ * NP_ * 768) return;
    int k = idx % 768;
    int bp = idx / 768;
    int pi = bp % NP_, b = bp / NP_;
    int gi = pi / 14, gj = pi % 14;
    int c = k >> 8, r = k & 255, p = r >> 4, q = r & 15;
    xcol[idx] = x[((size_t)(b * 3 + c) * 224 + gi * 16 + p) * 224 + gj * 16 + q];
}

// ---------------- assemble hidden: patches + cls + pos ----------------
__global__ __launch_bounds__(256) void assemble_kernel(const float* __restrict__ patchbuf,
                                                       const float* __restrict__ cls,
                                                       const float* __restrict__ pos,
                                                       float* __restrict__ hidden) {
    int idx = blockIdx.x * 256 + threadIdx.x;
    if (idx >= ROWS * E_) return;
    int e = idx % E_;
    int bt = idx / E_;
    int tok = bt % L_, b = bt / L_;
    float v;
    if (tok == 98) v = cls[e];
    else {
        int pi = tok < 98 ? tok : tok - 1;
        v = patchbuf[(size_t)(b * NP_ + pi) * E_ + e];
    }
    hidden[idx] = v + pos[tok * E_ + e];
}

// ---------------- bf16 MFMA GEMM ----------------
// C = A(MxK)*W(NxK fp32)^T + bias.  K % 32 == 0 required.
// amode 0: A fp32 (A0v/A1v by blockIdx.z)
// amode 4: A bf16 (A0v/A1v by blockIdx.z)
// amode 1: A = 0.5*(A0v + A1v), both bf16 (dir-average fold)
__global__ __launch_bounds__(256) void gemm_mfma_kernel(
    const void* A0v, const void* A1v, int lda,
    const float* __restrict__ W0, const float* __restrict__ W1,
    const float* __restrict__ bias,
    float* C0, float* C1, int ldc, int M, int N, int K, int amode) {
    __shared__ unsigned short As[128][32];
    __shared__ unsigned short Ws[128][32];
    const int tid = threadIdx.x;
    const int wave = tid >> 6, lane = tid & 63;
    const int wr = wave >> 1, wc = wave & 1;
    const int bm = blockIdx.y * 128, bn = blockIdx.x * 128;
    const int fr = lane & 15, fq = lane >> 4;
    const int r = tid >> 3, c4 = tid & 7;
    const float* W = blockIdx.z ? W1 : W0;
    float* C = blockIdx.z ? C1 : C0;
    const void* Av = blockIdx.z ? A1v : A0v;
    f32x4 acc[4][4] = {};

    for (int k0 = 0; k0 < K; k0 += 32) {
        __syncthreads();
        const int kbase = k0 + c4 * 4;
#pragma unroll
        for (int it = 0; it < 4; ++it) {
            int row = it * 32 + r;
            int gm = bm + row;
            ushort4 ua = {0, 0, 0, 0};
            if (gm < M) {
                if (amode == 0) {
                    const float* A = (const float*)Av;
                    float4 va = *(const float4*)&A[(size_t)gm * lda + kbase];
                    ua.x = f2bf(va.x); ua.y = f2bf(va.y);
                    ua.z = f2bf(va.z); ua.w = f2bf(va.w);
                } else if (amode == 1) {
                    const unsigned short* Af = (const unsigned short*)A0v;
                    const unsigned short* Ab = (const unsigned short*)A1v;
                    size_t off = (size_t)gm * lda + kbase;
                    ushort4 uf = *(const ushort4*)&Af[off];
                    ushort4 ub = *(const ushort4*)&Ab[off];
                    ua.x = f2bf((bf2f(uf.x) + bf2f(ub.x)) * 0.5f);
                    ua.y = f2bf((bf2f(uf.y) + bf2f(ub.y)) * 0.5f);
                    ua.z = f2bf((bf2f(uf.z) + bf2f(ub.z)) * 0.5f);
                    ua.w = f2bf((bf2f(uf.w) + bf2f(ub.w)) * 0.5f);
                } else {
                    const unsigned short* A = (const unsigned short*)Av;
                    ua = *(const ushort4*)&A[(size_t)gm * lda + kbase];
                }
            }
            *(ushort4*)&As[row][c4 * 4] = ua;
            int gn = bn + row;
            ushort4 uw = {0, 0, 0, 0};
            if (gn < N) {
                float4 vw = *(const float4*)&W[(size_t)gn * K + kbase];
                uw.x = f2bf(vw.x); uw.y = f2bf(vw.y);
                uw.z = f2bf(vw.z); uw.w = f2bf(vw.w);
            }
            *(ushort4*)&Ws[row][c4 * 4] = uw;
        }
        __syncthreads();
        bf16x8 af[4], bfr[4];
#pragma unroll
        for (int i = 0; i < 4; ++i) {
            af[i]  = *(const bf16x8*)&As[wr * 64 + i * 16 + fr][fq * 8];
            bfr[i] = *(const bf16x8*)&Ws[wc * 64 + i * 16 + fr][fq * 8];
        }
#pragma unroll
        for (int i = 0; i < 4; ++i)
#pragma unroll
            for (int j = 0; j < 4; ++j)
                acc[i][j] =
                    __builtin_amdgcn_mfma_f32_16x16x32_bf16(af[i], bfr[j], acc[i][j], 0, 0, 0);
    }

#pragma unroll
    for (int j = 0; j < 4; ++j) {
        int n = bn + wc * 64 + j * 16 + fr;
        if (n >= N) continue;
        float bv = bias ? bias[n] : 0.f;
#pragma unroll
        for (int i = 0; i < 4; ++i) {
#pragma unroll
            for (int rr = 0; rr < 4; ++rr) {
                int m = bm + wr * 64 + i * 16 + fq * 4 + rr;
                if (m < M) C[(size_t)m * ldc + n] = acc[i][j][rr] + bv;
            }
        }
    }
}

// ---------------- fused residual += hidden ; out = LayerNorm(residual) ----------------
__global__ __launch_bounds__(256) void resid_ln_kernel(float* __restrict__ residual,
                                                       const float* __restrict__ hidden,
                                                       const float* __restrict__ w,
                                                       const float* __restrict__ b,
                                                       float* __restrict__ out,
                                                       int nrows) {
    int row = blockIdx.x * 4 + (threadIdx.x >> 6);
    int lane = threadIdx.x & 63;
    if (row >= nrows) return;
    const float* rp = residual + (size_t)row * E_;
    const float* hp = hidden + (size_t)row * E_;
    float v[6];
    float sum = 0.f;
#pragma unroll
    for (int i = 0; i < 6; ++i) {
        int c = lane + i * 64;
        float x = rp[c] + hp[c];
        v[i] = x;
        sum += x;
    }
#pragma unroll
    for (int o = 32; o; o >>= 1) sum += __shfl_xor(sum, o);
    float mean = sum * (1.f / E_);
    float vs = 0.f;
#pragma unroll
    for (int i = 0; i < 6; ++i) {
        float d = v[i] - mean;
        vs += d * d;
    }
#pragma unroll
    for (int o = 32; o; o >>= 1) vs += __shfl_xor(vs, o);
    float rstd = rsqrtf(vs * (1.f / E_) + 1e-5f);
#pragma unroll
    for (int i = 0; i < 6; ++i) {
        int c = lane + i * 64;
        residual[(size_t)row * E_ + c] = v[i];
        out[(size_t)row * E_ + c] = (v[i] - mean) * rstd * w[c] + b[c];
    }
}

// ------- causal conv1d + SiLU -> bf16, both dirs; dir0 also emits silu(z) bf16 --------
__global__ __launch_bounds__(256) void conv_silu2b_kernel(const float* __restrict__ xz,
                                                          const float* __restrict__ cw_f,
                                                          const float* __restrict__ cb_f,
                                                          const float* __restrict__ cw_b,
                                                          const float* __restrict__ cb_b,
                                                          unsigned short* __restrict__ xc_f,
                                                          unsigned short* __restrict__ xc_b,
                                                          unsigned short* __restrict__ zsilu) {
    int rev = blockIdx.y;
    const float* cw = rev ? cw_b : cw_f;
    const float* cb = rev ? cb_b : cb_f;
    unsigned short* xc = rev ? xc_b : xc_f;
    int idx = blockIdx.x * 256 + threadIdx.x;
    if (idx >= B_ * L_ * DI_) return;
    int d = idx % DI_;
    int bt = idx / DI_;
    int t = bt % L_, b = bt / L_;
    float acc = cb[d];
#pragma unroll
    for (int k = 0; k < 4; ++k) {
        int tt = t - 3 + k;
        if (tt >= 0) {
            int pos = rev ? (L_ - 1 - tt) : tt;
            acc += cw[d * 4 + k] * xz[(size_t)(b * L_ + pos) * (2 * DI_) + d];
        }
    }
    xc[idx] = f2bf(silu_f(acc));
    if (rev == 0) {
        float zv = xz[(size_t)bt * (2 * DI_) + DI_ + d];
        zsilu[idx] = f2bf(silu_f(zv));
    }
}

// ---------------- chunk-parallel SSM scan, 8 d's/block, XCD-affinity swizzle ----------
// 1-D grid of 6144; decode so all blocks of one (b,dir) pair share an XCD (bid%8).
// 512 threads = 8 dd (wave) x 4 t-chunks x 16 states; chunks of 50 (4*50 >= 197).
__global__ __launch_bounds__(512) void scan8_kernel(
    const unsigned short* __restrict__ xcl_f, const unsigned short* __restrict__ xcl_b,
    const float* __restrict__ xdbl_f, const float* __restrict__ xdbl_b,
    const unsigned short* __restrict__ zsilu,
    const float* __restrict__ dtw_f, const float* __restrict__ dtw_b,
    const float* __restrict__ dtb_f, const float* __restrict__ dtb_b,
    const float* __restrict__ Alog_f, const float* __restrict__ Alog_b,
    const float* __restrict__ Dv_f, const float* __restrict__ Dv_b,
    unsigned short* __restrict__ yout_f, unsigned short* __restrict__ yout_b) {
    // swizzled decode: bid%8 == pair%8 -> same XCD serves one (b,dir)'s blocks
    int bid = blockIdx.x;
    int xcd = bid & 7;
    int rdec = bid >> 3;
    int dg = rdec % 96;
    int ph = rdec / 96;
    int p = ph * 8 + xcd;
    const int b = p >> 1, dir = p & 1;
    const int d0 = dg * 8;

    const unsigned short* xcl = dir ? xcl_b : xcl_f;
    const float* xdbl = dir ? xdbl_b : xdbl_f;
    const float* dtw  = dir ? dtw_b : dtw_f;
    const float* dtbp = dir ? dtb_b : dtb_f;
    const float* Alog = dir ? Alog_b : Alog_f;
    const float* Dv   = dir ? Dv_b : Dv_f;
    unsigned short* yout = dir ? yout_b : yout_f;
    const int tid = threadIdx.x;

    __shared__ float dt_s[8][200], g_s[8][200], u_s[8][200], z_s[8][200], y_s[8][200];
    __shared__ float B_s[200][17], C_s[200][17];
    __shared__ float Ps[8][4][16], Ss[8][4][16], hin[8][4][16];
    __shared__ float dtw_s[8][24];

    if (tid < 192) dtw_s[tid / 24][tid % 24] = dtw[(d0 + tid / 24) * 24 + tid % 24];
    __syncthreads();

    // stage B, C
    for (int e = tid; e < 3200; e += 512) {
        int t = e >> 4, nn = e & 15;
        float Bv = 0.f, Cv = 0.f;
        if (t < L_) {
            const float* xr = &xdbl[(size_t)(b * L_ + t) * 56];
            Bv = xr[24 + nn];
            Cv = xr[40 + nn];
        }
        B_s[t][nn] = Bv;
        C_s[t][nn] = Cv;
    }
    // stage u, z(at output pos), dt (fused dt_proj), g = dt*u
    for (int e = tid; e < 1600; e += 512) {
        int dd = e & 7, t = e >> 3;
        float uv = 0.f, dtv = 0.f, zv = 0.f;
        if (t < L_) {
            size_t row = (size_t)(b * L_ + t);
            int pos = dir ? (L_ - 1 - t) : t;
            uv = bf2f(xcl[row * DI_ + d0 + dd]);
            zv = bf2f(zsilu[(size_t)(b * L_ + pos) * DI_ + d0 + dd]);
            const float* xr = &xdbl[row * 56];
            float acc = dtbp[d0 + dd];
#pragma unroll
            for (int rr = 0; rr < 24; ++rr) acc += xr[rr] * dtw_s[dd][rr];
            dtv = (acc > 20.f) ? acc : log1pf(__expf(acc));
        }
        u_s[dd][t] = uv;
        z_s[dd][t] = zv;
        dt_s[dd][t] = dtv;
        g_s[dd][t] = dtv * uv;
    }
    __syncthreads();

    const int dd = tid >> 6;           // wave = d within group
    const int tt = (tid >> 4) & 3;     // chunk
    const int n = tid & 15;            // state
    const float An = -__expf(Alog[(d0 + dd) * DS_ + n]);
    const int t0 = tt * 50;

    float P = 1.f, S = 0.f;
#pragma unroll 10
    for (int i = 0; i < 50; ++i) {
        int t = t0 + i;
        float a = __expf(dt_s[dd][t] * An);
        S = S * a + g_s[dd][t] * B_s[t][n];
        P *= a;
    }
    Ps[dd][tt][n] = P;
    Ss[dd][tt][n] = S;
    __syncthreads();
    if (tid < 128) {
        int cdd = tid >> 4, cn = tid & 15;
        float h = 0.f;
#pragma unroll
        for (int c = 0; c < 4; ++c) {
            hin[cdd][c][cn] = h;
            h = Ps[cdd][c][cn] * h + Ss[cdd][c][cn];
        }
    }
    __syncthreads();

    float h = hin[dd][tt][n];
    const float Dval = Dv[d0 + dd];
#pragma unroll 10
    for (int i = 0; i < 50; ++i) {
        int t = t0 + i;
        float a = __expf(dt_s[dd][t] * An);
        h = a * h + g_s[dd][t] * B_s[t][n];
        float y = h * C_s[t][n];
        y += __shfl_xor(y, 1);
        y += __shfl_xor(y, 2);
        y += __shfl_xor(y, 4);
        y += __shfl_xor(y, 8);
        if (n == 0) y_s[dd][t] = (y + u_s[dd][t] * Dval) * z_s[dd][t];
    }
    __syncthreads();
    // coalesced row-major writeout (y value for output position pos lives at scan index t)
    for (int e = tid; e < 1600; e += 512) {
        int dd2 = e & 7, t = e >> 3;
        if (t < L_) {
            int pos = dir ? (L_ - 1 - t) : t;
            yout[(size_t)(b * L_ + pos) * DI_ + d0 + dd2] = f2bf(y_s[dd2][t]);
        }
    }
}

// ---------------- feature extraction ----------------
__global__ __launch_bounds__(256) void feat_kernel(const float* __restrict__ hidden,
                                                   float* __restrict__ out) {
    int idx = blockIdx.x * 256 + threadIdx.x;
    if (idx >= FEAT) return;
    int p = idx % NP_;
    int be = idx / NP_;
    int e = be % E_, b = be / E_;
    int tok = p < 98 ? p : p + 1;
    out[idx] = hidden[(size_t)(b * L_ + tok) * E_ + e];
}

static inline void launch_gemm_f32(const float* A, int lda, const float* W, const float* bias,
                                   float* C, int ldc, int M, int N, int K,
                                   hipStream_t stream) {
    dim3 grid((N + 127) / 128, (M + 127) / 128, 1);
    hipLaunchKernelGGL(gemm_mfma_kernel, grid, dim3(256), 0, stream, (const void*)A, nullptr,
                       lda, W, nullptr, bias, C, nullptr, ldc, M, N, K, 0);
}

extern "C" void kernel_launch(void* const* d_in, const int* in_sizes, int n_in, void* d_out,
                              int out_size, void* d_ws, size_t ws_size, hipStream_t stream) {
    const float* x        = (const float*)d_in[0];
    const float* patch_w  = (const float*)d_in[1];
    const float* patch_b  = (const float*)d_in[2];
    const float* cls_tok  = (const float*)d_in[3];
    const float* pos_emb  = (const float*)d_in[4];
    const float* norm_w   = (const float*)d_in[5];
    const float* norm_b   = (const float*)d_in[6];
    const float* in_proj  = (const float*)d_in[7];
    const float* conv_w   = (const float*)d_in[8];
    const float* conv_b   = (const float*)d_in[9];
    const float* xproj_w  = (const float*)d_in[10];
    const float* dtproj_w = (const float*)d_in[11];
    const float* dtproj_b = (const float*)d_in[12];
    const float* A_log    = (const float*)d_in[13];
    const float* D_param  = (const float*)d_in[14];
    const float* conv_wb  = (const float*)d_in[15];
    const float* conv_bb  = (const float*)d_in[16];
    const float* xproj_wb = (const float*)d_in[17];
    const float* dtproj_wb= (const float*)d_in[18];
    const float* dtproj_bb= (const float*)d_in[19];
    const float* A_logb   = (const float*)d_in[20];
    const float* D_paramb = (const float*)d_in[21];
    const float* out_proj = (const float*)d_in[22];
    const float* normf_w  = (const float*)d_in[23];
    const float* normf_b  = (const float*)d_in[24];
    float* out = (float*)d_out;

    float* ws       = (float*)d_ws;
    float* residual = ws;                                    // 2,420,736 f32
    float* hidden   = residual + OUT0;                       // 2,420,736 f32
    float* xz       = hidden + OUT0;                         // 9,682,944 f32
    unsigned short* xcl_f = (unsigned short*)(xz + (size_t)ROWS * 1536);  // ROWS*768 u16
    unsigned short* xcl_b = xcl_f + (size_t)ROWS * DI_;
    unsigned short* zsilu = xcl_b + (size_t)ROWS * DI_;
    float* xdbl_f   = (float*)(zsilu + (size_t)ROWS * DI_);  // 353,024 f32
    float* xdbl_b   = xdbl_f + (size_t)ROWS * 56;
    unsigned short* yout_f = (unsigned short*)(xdbl_b + (size_t)ROWS * 56);
    unsigned short* yout_b = yout_f + (size_t)ROWS * DI_;
    // overlays (timeline-disjoint)
    float* hn       = (float*)yout_f;  // alive LN -> in_proj; yout alive scan -> out_proj
    float* xcol     = xz;              // pre-layer only
    float* patchbuf = (float*)yout_f;  // pre-layer only

    hipMemsetAsync(residual, 0, (size_t)OUT0 * sizeof(float), stream);

    // patch embedding
    hipLaunchKernelGGL(im2col_kernel, dim3((B_ * NP_ * 768 + 255) / 256), dim3(256), 0, stream,
                       x, xcol);
    launch_gemm_f32(xcol, 768, patch_w, patch_b, patchbuf, E_, B_ * NP_, E_, 768, stream);
    hipLaunchKernelGGL(assemble_kernel, dim3((ROWS * E_ + 255) / 256), dim3(256), 0, stream,
                       patchbuf, cls_tok, pos_emb, hidden);

    int fidx = 0;
    for (int i = 0; i < 24; ++i) {
        hipLaunchKernelGGL(resid_ln_kernel, dim3(ROWS / 4), dim3(256), 0, stream, residual,
                           hidden, norm_w + i * E_, norm_b + i * E_, hn, ROWS);
        launch_gemm_f32(hn, E_, in_proj + (size_t)i * 1536 * E_, nullptr, xz, 1536, ROWS, 1536,
                        E_, stream);
        hipLaunchKernelGGL(conv_silu2b_kernel, dim3(B_ * L_ * DI_ / 256, 2), dim3(256), 0,
                           stream, xz, conv_w + (size_t)i * DI_ * 4, conv_b + (size_t)i * DI_,
                           conv_wb + (size_t)i * DI_ * 4, conv_bb + (size_t)i * DI_, xcl_f,
                           xcl_b, zsilu);
        // batched x_proj GEMM over both directions (bf16 A)
        {
            dim3 grid(1, (ROWS + 127) / 128, 2);
            hipLaunchKernelGGL(gemm_mfma_kernel, grid, dim3(256), 0, stream,
                               (const void*)xcl_f, (const void*)xcl_b, DI_,
                               xproj_w + (size_t)i * 56 * DI_, xproj_wb + (size_t)i * 56 * DI_,
                               nullptr, xdbl_f, xdbl_b, 56, ROWS, 56, DI_, 4);
        }
        hipLaunchKernelGGL(scan8_kernel, dim3(6144), dim3(512), 0, stream, xcl_f, xcl_b,
                           xdbl_f, xdbl_b, zsilu, dtproj_w + (size_t)i * DI_ * DR_,
                           dtproj_wb + (size_t)i * DI_ * DR_, dtproj_b + (size_t)i * DI_,
                           dtproj_bb + (size_t)i * DI_, A_log + (size_t)i * DI_ * DS_,
                           A_logb + (size_t)i * DI_ * DS_, D_param + (size_t)i * DI_,
                           D_paramb + (size_t)i * DI_, yout_f, yout_b);
        // out_proj: A = 0.5*(yout_f + yout_b), both bf16 row-major
        {
            dim3 grid((E_ + 127) / 128, (ROWS + 127) / 128, 1);
            hipLaunchKernelGGL(gemm_mfma_kernel, grid, dim3(256), 0, stream,
                               (const void*)yout_f, (const void*)yout_b, DI_,
                               out_proj + (size_t)i * E_ * DI_, nullptr, nullptr, hidden,
                               nullptr, E_, ROWS, E_, DI_, 1);
        }
        if (i == 5 || i == 11 || i == 17 || i == 23) {
            hipLaunchKernelGGL(feat_kernel, dim3(FEAT / 256), dim3(256), 0, stream, hidden,
                               out + OUT0 + (size_t)fidx * FEAT);
            ++fidx;
        }
    }
    hipLaunchKernelGGL(resid_ln_kernel, dim3(ROWS / 4), dim3(256), 0, stream, residual, hidden,
                       normf_w, normf_b, out, ROWS);
}

// Round 10
// 11212.397 us; speedup vs baseline: 1.1018x; 1.1018x over previous
//
#include <hip/hip_runtime.h>
#include <math.h>

#define B_   32
#define L_   197
#define E_   384
#define DI_  768
#define DS_  16
#define DR_  24
#define NP_  196
#define ROWS (B_ * L_)         // 6304
#define OUT0 (ROWS * E_)       // 2420736
#define FEAT (B_ * E_ * NP_)   // 2408448

typedef __attribute__((ext_vector_type(8))) short bf16x8;
typedef __attribute__((ext_vector_type(4))) float f32x4;

__device__ __forceinline__ float silu_f(float x) { return x / (1.f + __expf(-x)); }

__device__ __forceinline__ unsigned short f2bf(float x) {
    unsigned int u = __float_as_uint(x);
    u += 0x7fffu + ((u >> 16) & 1u);
    return (unsigned short)(u >> 16);
}
__device__ __forceinline__ float bf2f(unsigned short u) {
    return __uint_as_float((unsigned int)u << 16);
}

// ---------------- im2col for patch embedding ----------------
__global__ __launch_bounds__(256) void im2col_kernel(const float* __restrict__ x,
                                                     float* __restrict__ xcol) {
    int idx = blockIdx.x * 256 + threadIdx.x;
    if (idx >= B_ * NP_ * 768) return;
    int k = idx % 768;
    int bp = idx / 768;
    int pi = bp % NP_, b = bp / NP_;
    int gi = pi / 14, gj = pi % 14;
    int c = k >> 8, r = k & 255, p = r >> 4, q = r & 15;
    xcol[idx] = x[((size_t)(b * 3 + c) * 224 + gi * 16 + p) * 224 + gj * 16 + q];
}

// ---------------- assemble hidden: patches + cls + pos ----------------
__global__ __launch_bounds__(256) void assemble_kernel(const float* __restrict__ patchbuf,
                                                       const float* __restrict__ cls,
                                                       const float* __restrict__ pos,
                                                       float* __restrict__ hidden) {
    int idx = blockIdx.x * 256 + threadIdx.x;
    if (idx >= ROWS * E_) return;
    int e = idx % E_;
    int bt = idx / E_;
    int tok = bt % L_, b = bt / L_;
    float v;
    if (tok == 98) v = cls[e];
    else {
        int pi = tok < 98 ? tok : tok - 1;
        v = patchbuf[(size_t)(b * NP_ + pi) * E_ + e];
    }
    hidden[idx] = v + pos[tok * E_ + e];
}

// ---------------- bf16 MFMA GEMM ----------------
// C = A(MxK)*W(NxK fp32)^T + bias.  K % 32 == 0 required.
// amode 0: A fp32 (A0v/A1v by blockIdx.z)
// amode 4: A bf16 (A0v/A1v by blockIdx.z)
// amode 1: A = 0.5*(A0v + A1v), both bf16 (dir-average fold)
__global__ __launch_bounds__(256) void gemm_mfma_kernel(
    const void* A0v, const void* A1v, int lda,
    const float* __restrict__ W0, const float* __restrict__ W1,
    const float* __restrict__ bias,
    float* C0, float* C1, int ldc, int M, int N, int K, int amode) {
    __shared__ unsigned short As[128][32];
    __shared__ unsigned short Ws[128][32];
    const int tid = threadIdx.x;
    const int wave = tid >> 6, lane = tid & 63;
    const int wr = wave >> 1, wc = wave & 1;
    const int bm = blockIdx.y * 128, bn = blockIdx.x * 128;
    const int fr = lane & 15, fq = lane >> 4;
    const int r = tid >> 3, c4 = tid & 7;
    const float* W = blockIdx.z ? W1 : W0;
    float* C = blockIdx.z ? C1 : C0;
    const void* Av = blockIdx.z ? A1v : A0v;
    f32x4 acc[4][4] = {};

    for (int k0 = 0; k0 < K; k0 += 32) {
        __syncthreads();
        const int kbase = k0 + c4 * 4;
#pragma unroll
        for (int it = 0; it < 4; ++it) {
            int row = it * 32 + r;
            int gm = bm + row;
            ushort4 ua = {0, 0, 0, 0};
            if (gm < M) {
                if (amode == 0) {
                    const float* A = (const float*)Av;
                    float4 va = *(const float4*)&A[(size_t)gm * lda + kbase];
                    ua.x = f2bf(va.x); ua.y = f2bf(va.y);
                    ua.z = f2bf(va.z); ua.w = f2bf(va.w);
                } else if (amode == 1) {
                    const unsigned short* Af = (const unsigned short*)A0v;
                    const unsigned short* Ab = (const unsigned short*)A1v;
                    size_t off = (size_t)gm * lda + kbase;
                    ushort4 uf = *(const ushort4*)&Af[off];
                    ushort4 ub = *(const ushort4*)&Ab[off];
                    ua.x = f2bf((bf2f(uf.x) + bf2f(ub.x)) * 0.5f);
                    ua.y = f2bf((bf2f(uf.y) + bf2f(ub.y)) * 0.5f);
                    ua.z = f2bf((bf2f(uf.z) + bf2f(ub.z)) * 0.5f);
                    ua.w = f2bf((bf2f(uf.w) + bf2f(ub.w)) * 0.5f);
                } else {
                    const unsigned short* A = (const unsigned short*)Av;
                    ua = *(const ushort4*)&A[(size_t)gm * lda + kbase];
                }
            }
            *(ushort4*)&As[row][c4 * 4] = ua;
            int gn = bn + row;
            ushort4 uw = {0, 0, 0, 0};
            if (gn < N) {
                float4 vw = *(const float4*)&W[(size_t)gn * K + kbase];
                uw.x = f2bf(vw.x); uw.y = f2bf(vw.y);
                uw.z = f2bf(vw.z); uw.w = f2bf(vw.w);
            }
            *(ushort4*)&Ws[row][c4 * 4] = uw;
        }
        __syncthreads();
        bf16x8 af[4], bfr[4];
#pragma unroll
        for (int i = 0; i < 4; ++i) {
            af[i]  = *(const bf16x8*)&As[wr * 64 + i * 16 + fr][fq * 8];
            bfr[i] = *(const bf16x8*)&Ws[wc * 64 + i * 16 + fr][fq * 8];
        }
#pragma unroll
        for (int i = 0; i < 4; ++i)
#pragma unroll
            for (int j = 0; j < 4; ++j)
                acc[i][j] =
                    __builtin_amdgcn_mfma_f32_16x16x32_bf16(af[i], bfr[j], acc[i][j], 0, 0, 0);
    }

#pragma unroll
    for (int j = 0; j < 4; ++j) {
        int n = bn + wc * 64 + j * 16 + fr;
        if (n >= N) continue;
        float bv = bias ? bias[n] : 0.f;
#pragma unroll
        for (int i = 0; i < 4; ++i) {
#pragma unroll
            for (int rr = 0; rr < 4; ++rr) {
                int m = bm + wr * 64 + i * 16 + fq * 4 + rr;
                if (m < M) C[(size_t)m * ldc + n] = acc[i][j][rr] + bv;
            }
        }
    }
}

// ---------------- fused residual += hidden ; out = LayerNorm(residual) ----------------
__global__ __launch_bounds__(256) void resid_ln_kernel(float* __restrict__ residual,
                                                       const float* __restrict__ hidden,
                                                       const float* __restrict__ w,
                                                       const float* __restrict__ b,
                                                       float* __restrict__ out,
                                                       int nrows) {
    int row = blockIdx.x * 4 + (threadIdx.x >> 6);
    int lane = threadIdx.x & 63;
    if (row >= nrows) return;
    const float* rp = residual + (size_t)row * E_;
    const float* hp = hidden + (size_t)row * E_;
    float v[6];
    float sum = 0.f;
#pragma unroll
    for (int i = 0; i < 6; ++i) {
        int c = lane + i * 64;
        float x = rp[c] + hp[c];
        v[i] = x;
        sum += x;
    }
#pragma unroll
    for (int o = 32; o; o >>= 1) sum += __shfl_xor(sum, o);
    float mean = sum * (1.f / E_);
    float vs = 0.f;
#pragma unroll
    for (int i = 0; i < 6; ++i) {
        float d = v[i] - mean;
        vs += d * d;
    }
#pragma unroll
    for (int o = 32; o; o >>= 1) vs += __shfl_xor(vs, o);
    float rstd = rsqrtf(vs * (1.f / E_) + 1e-5f);
#pragma unroll
    for (int i = 0; i < 6; ++i) {
        int c = lane + i * 64;
        residual[(size_t)row * E_ + c] = v[i];
        out[(size_t)row * E_ + c] = (v[i] - mean) * rstd * w[c] + b[c];
    }
}

// ------- causal conv1d + SiLU -> bf16, both dirs; dir0 also emits silu(z) bf16 --------
__global__ __launch_bounds__(256) void conv_silu2b_kernel(const float* __restrict__ xz,
                                                          const float* __restrict__ cw_f,
                                                          const float* __restrict__ cb_f,
                                                          const float* __restrict__ cw_b,
                                                          const float* __restrict__ cb_b,
                                                          unsigned short* __restrict__ xc_f,
                                                          unsigned short* __restrict__ xc_b,
                                                          unsigned short* __restrict__ zsilu) {
    int rev = blockIdx.y;
    const float* cw = rev ? cw_b : cw_f;
    const float* cb = rev ? cb_b : cb_f;
    unsigned short* xc = rev ? xc_b : xc_f;
    int idx = blockIdx.x * 256 + threadIdx.x;
    if (idx >= B_ * L_ * DI_) return;
    int d = idx % DI_;
    int bt = idx / DI_;
    int t = bt % L_, b = bt / L_;
    float acc = cb[d];
#pragma unroll
    for (int k = 0; k < 4; ++k) {
        int tt = t - 3 + k;
        if (tt >= 0) {
            int pos = rev ? (L_ - 1 - tt) : tt;
            acc += cw[d * 4 + k] * xz[(size_t)(b * L_ + pos) * (2 * DI_) + d];
        }
    }
    xc[idx] = f2bf(silu_f(acc));
    if (rev == 0) {
        float zv = xz[(size_t)bt * (2 * DI_) + DI_ + d];
        zsilu[idx] = f2bf(silu_f(zv));
    }
}

// ---------------- chunk-parallel SSM scan, 8 d's/block, XCD-affinity swizzle ----------
// LDS-diet version: bf16 staging (dt stays f32), bank-conflict-free n-major B/C.
// 39.7 KB LDS -> 4 blocks/CU (full occupancy). 512 thr = 8 dd x 4 chunks x 16 states.
__global__ __launch_bounds__(512, 8) void scan8_kernel(
    const unsigned short* __restrict__ xcl_f, const unsigned short* __restrict__ xcl_b,
    const float* __restrict__ xdbl_f, const float* __restrict__ xdbl_b,
    const unsigned short* __restrict__ zsilu,
    const float* __restrict__ dtw_f, const float* __restrict__ dtw_b,
    const float* __restrict__ dtb_f, const float* __restrict__ dtb_b,
    const float* __restrict__ Alog_f, const float* __restrict__ Alog_b,
    const float* __restrict__ Dv_f, const float* __restrict__ Dv_b,
    unsigned short* __restrict__ yout_f, unsigned short* __restrict__ yout_b) {
    // swizzled decode: bid%8 == pair%8 -> same XCD serves one (b,dir)'s blocks
    int bid = blockIdx.x;
    int xcd = bid & 7;
    int rdec = bid >> 3;
    int dg = rdec % 96;
    int ph = rdec / 96;
    int p = ph * 8 + xcd;
    const int b = p >> 1, dir = p & 1;
    const int d0 = dg * 8;

    const unsigned short* xcl = dir ? xcl_b : xcl_f;
    const float* xdbl = dir ? xdbl_b : xdbl_f;
    const float* dtw  = dir ? dtw_b : dtw_f;
    const float* dtbp = dir ? dtb_b : dtb_f;
    const float* Alog = dir ? Alog_b : Alog_f;
    const float* Dv   = dir ? Dv_b : Dv_f;
    unsigned short* yout = dir ? yout_b : yout_f;
    const int tid = threadIdx.x;

    __shared__ float dt_s[8][200];                        // 6.4 KB (f32: exp-sensitive)
    __shared__ unsigned short g_s[8][200];                // 3.2 KB
    __shared__ unsigned short u_s[8][200];                // 3.2 KB
    __shared__ unsigned short z_s[8][200];                // 3.2 KB
    __shared__ unsigned short y_s[8][200];                // 3.2 KB
    __shared__ unsigned short B_s[16][212];               // 6.8 KB  n-major, bank-free
    __shared__ unsigned short C_s[16][212];               // 6.8 KB
    __shared__ float Ps[8][4][16], Ss[8][4][16], hin[8][4][16];  // 6 KB
    __shared__ float dtw_s[8][24];                        // 0.77 KB

    if (tid < 192) dtw_s[tid / 24][tid % 24] = dtw[(d0 + tid / 24) * 24 + tid % 24];
    __syncthreads();

    // stage B, C into n-major bf16 (coalesced xdbl row reads)
    for (int e = tid; e < 3200; e += 512) {
        int t = e >> 4, nn = e & 15;
        float Bv = 0.f, Cv = 0.f;
        if (t < L_) {
            const float* xr = &xdbl[(size_t)(b * L_ + t) * 56];
            Bv = xr[24 + nn];
            Cv = xr[40 + nn];
        }
        B_s[nn][t] = f2bf(Bv);
        C_s[nn][t] = f2bf(Cv);
    }
    // stage dt (f32), g=dt*u (bf16), u, z — paired t's per thread (ushort2/float2 writes)
    for (int e = tid; e < 800; e += 512) {
        int dd = e & 7, q = e >> 3;             // q = 0..99 -> t = 2q, 2q+1
        float dtv[2], uv[2], zv[2];
#pragma unroll
        for (int h = 0; h < 2; ++h) {
            int t = 2 * q + h;
            dtv[h] = 0.f; uv[h] = 0.f; zv[h] = 0.f;
            if (t < L_) {
                size_t row = (size_t)(b * L_ + t);
                int pos = dir ? (L_ - 1 - t) : t;
                uv[h] = bf2f(xcl[row * DI_ + d0 + dd]);
                zv[h] = bf2f(zsilu[(size_t)(b * L_ + pos) * DI_ + d0 + dd]);
                const float* xr = &xdbl[row * 56];
                float acc = dtbp[d0 + dd];
#pragma unroll
                for (int rr = 0; rr < 24; ++rr) acc += xr[rr] * dtw_s[dd][rr];
                dtv[h] = (acc > 20.f) ? acc : log1pf(__expf(acc));
            }
        }
        *(float2*)&dt_s[dd][2 * q] = make_float2(dtv[0], dtv[1]);
        ushort2 ug = {f2bf(dtv[0] * uv[0]), f2bf(dtv[1] * uv[1])};
        ushort2 uu = {f2bf(uv[0]), f2bf(uv[1])};
        ushort2 uz = {f2bf(zv[0]), f2bf(zv[1])};
        *(ushort2*)&g_s[dd][2 * q] = ug;
        *(ushort2*)&u_s[dd][2 * q] = uu;
        *(ushort2*)&z_s[dd][2 * q] = uz;
    }
    __syncthreads();

    const int dd = tid >> 6;           // wave = d within group
    const int tt = (tid >> 4) & 3;     // chunk
    const int n = tid & 15;            // state
    const float An = -__expf(Alog[(d0 + dd) * DS_ + n]);
    const int t0 = tt * 50;

    float P = 1.f, S = 0.f;
#pragma unroll 10
    for (int i = 0; i < 50; ++i) {
        int t = t0 + i;
        float a = __expf(dt_s[dd][t] * An);
        S = S * a + bf2f(g_s[dd][t]) * bf2f(B_s[n][t]);
        P *= a;
    }
    Ps[dd][tt][n] = P;
    Ss[dd][tt][n] = S;
    __syncthreads();
    if (tid < 128) {
        int cdd = tid >> 4, cn = tid & 15;
        float h = 0.f;
#pragma unroll
        for (int c = 0; c < 4; ++c) {
            hin[cdd][c][cn] = h;
            h = Ps[cdd][c][cn] * h + Ss[cdd][c][cn];
        }
    }
    __syncthreads();

    float h = hin[dd][tt][n];
    const float Dval = Dv[d0 + dd];
#pragma unroll 10
    for (int i = 0; i < 50; ++i) {
        int t = t0 + i;
        float a = __expf(dt_s[dd][t] * An);
        h = a * h + bf2f(g_s[dd][t]) * bf2f(B_s[n][t]);
        float y = h * bf2f(C_s[n][t]);
        y += __shfl_xor(y, 1);
        y += __shfl_xor(y, 2);
        y += __shfl_xor(y, 4);
        y += __shfl_xor(y, 8);
        if (n == 0)
            y_s[dd][t] = f2bf((y + bf2f(u_s[dd][t]) * Dval) * bf2f(z_s[dd][t]));
    }
    __syncthreads();
    // coalesced row-major writeout (y value for output position pos lives at scan index t)
    for (int e = tid; e < 1600; e += 512) {
        int dd2 = e & 7, t = e >> 3;
        if (t < L_) {
            int pos = dir ? (L_ - 1 - t) : t;
            yout[(size_t)(b * L_ + pos) * DI_ + d0 + dd2] = y_s[dd2][t];
        }
    }
}

// ---------------- feature extraction ----------------
__global__ __launch_bounds__(256) void feat_kernel(const float* __restrict__ hidden,
                                                   float* __restrict__ out) {
    int idx = blockIdx.x * 256 + threadIdx.x;
    if (idx >= FEAT) return;
    int p = idx % NP_;
    int be = idx / NP_;
    int e = be % E_, b = be / E_;
    int tok = p < 98 ? p : p + 1;
    out[idx] = hidden[(size_t)(b * L_ + tok) * E_ + e];
}

static inline void launch_gemm_f32(const float* A, int lda, const float* W, const float* bias,
                                   float* C, int ldc, int M, int N, int K,
                                   hipStream_t stream) {
    dim3 grid((N + 127) / 128, (M + 127) / 128, 1);
    hipLaunchKernelGGL(gemm_mfma_kernel, grid, dim3(256), 0, stream, (const void*)A, nullptr,
                       lda, W, nullptr, bias, C, nullptr, ldc, M, N, K, 0);
}

extern "C" void kernel_launch(void* const* d_in, const int* in_sizes, int n_in, void* d_out,
                              int out_size, void* d_ws, size_t ws_size, hipStream_t stream) {
    const float* x        = (const float*)d_in[0];
    const float* patch_w  = (const float*)d_in[1];
    const float* patch_b  = (const float*)d_in[2];
    const float* cls_tok  = (const float*)d_in[3];
    const float* pos_emb  = (const float*)d_in[4];
    const float* norm_w   = (const float*)d_in[5];
    const float* norm_b   = (const float*)d_in[6];
    const float* in_proj  = (const float*)d_in[7];
    const float* conv_w   = (const float*)d_in[8];
    const float* conv_b   = (const float*)d_in[9];
    const float* xproj_w  = (const float*)d_in[10];
    const float* dtproj_w = (const float*)d_in[11];
    const float* dtproj_b = (const float*)d_in[12];
    const float* A_log    = (const float*)d_in[13];
    const float* D_param  = (const float*)d_in[14];
    const float* conv_wb  = (const float*)d_in[15];
    const float* conv_bb  = (const float*)d_in[16];
    const float* xproj_wb = (const float*)d_in[17];
    const float* dtproj_wb= (const float*)d_in[18];
    const float* dtproj_bb= (const float*)d_in[19];
    const float* A_logb   = (const float*)d_in[20];
    const float* D_paramb = (const float*)d_in[21];
    const float* out_proj = (const float*)d_in[22];
    const float* normf_w  = (const float*)d_in[23];
    const float* normf_b  = (const float*)d_in[24];
    float* out = (float*)d_out;

    float* ws       = (float*)d_ws;
    float* residual = ws;                                    // 2,420,736 f32
    float* hidden   = residual + OUT0;                       // 2,420,736 f32
    float* xz       = hidden + OUT0;                         // 9,682,944 f32
    unsigned short* xcl_f = (unsigned short*)(xz + (size_t)ROWS * 1536);  // ROWS*768 u16
    unsigned short* xcl_b = xcl_f + (size_t)ROWS * DI_;
    unsigned short* zsilu = xcl_b + (size_t)ROWS * DI_;
    float* xdbl_f   = (float*)(zsilu + (size_t)ROWS * DI_);  // 353,024 f32
    float* xdbl_b   = xdbl_f + (size_t)ROWS * 56;
    unsigned short* yout_f = (unsigned short*)(xdbl_b + (size_t)ROWS * 56);
    unsigned short* yout_b = yout_f + (size_t)ROWS * DI_;
    // overlays (timeline-disjoint)
    float* hn       = (float*)yout_f;  // alive LN -> in_proj; yout alive scan -> out_proj
    float* xcol     = xz;              // pre-layer only
    float* patchbuf = (float*)yout_f;  // pre-layer only

    hipMemsetAsync(residual, 0, (size_t)OUT0 * sizeof(float), stream);

    // patch embedding
    hipLaunchKernelGGL(im2col_kernel, dim3((B_ * NP_ * 768 + 255) / 256), dim3(256), 0, stream,
                       x, xcol);
    launch_gemm_f32(xcol, 768, patch_w, patch_b, patchbuf, E_, B_ * NP_, E_, 768, stream);
    hipLaunchKernelGGL(assemble_kernel, dim3((ROWS * E_ + 255) / 256), dim3(256), 0, stream,
                       patchbuf, cls_tok, pos_emb, hidden);

    int fidx = 0;
    for (int i = 0; i < 24; ++i) {
        hipLaunchKernelGGL(resid_ln_kernel, dim3(ROWS / 4), dim3(256), 0, stream, residual,
                           hidden, norm_w + i * E_, norm_b + i * E_, hn, ROWS);
        launch_gemm_f32(hn, E_, in_proj + (size_t)i * 1536 * E_, nullptr, xz, 1536, ROWS, 1536,
                        E_, stream);
        hipLaunchKernelGGL(conv_silu2b_kernel, dim3(B_ * L_ * DI_ / 256, 2), dim3(256), 0,
                           stream, xz, conv_w + (size_t)i * DI_ * 4, conv_b + (size_t)i * DI_,
                           conv_wb + (size_t)i * DI_ * 4, conv_bb + (size_t)i * DI_, xcl_f,
                           xcl_b, zsilu);
        // batched x_proj GEMM over both directions (bf16 A)
        {
            dim3 grid(1, (ROWS + 127) / 128, 2);
            hipLaunchKernelGGL(gemm_mfma_kernel, grid, dim3(256), 0, stream,
                               (const void*)xcl_f, (const void*)xcl_b, DI_,
                               xproj_w + (size_t)i * 56 * DI_, xproj_wb + (size_t)i * 56 * DI_,
                               nullptr, xdbl_f, xdbl_b, 56, ROWS, 56, DI_, 4);
        }
        hipLaunchKernelGGL(scan8_kernel, dim3(6144), dim3(512), 0, stream, xcl_f, xcl_b,
                           xdbl_f, xdbl_b, zsilu, dtproj_w + (size_t)i * DI_ * DR_,
                           dtproj_wb + (size_t)i * DI_ * DR_, dtproj_b + (size_t)i * DI_,
                           dtproj_bb + (size_t)i * DI_, A_log + (size_t)i * DI_ * DS_,
                           A_logb + (size_t)i * DI_ * DS_, D_param + (size_t)i * DI_,
                           D_paramb + (size_t)i * DI_, yout_f, yout_b);
        // out_proj: A = 0.5*(yout_f + yout_b), both bf16 row-major
        {
            dim3 grid((E_ + 127) / 128, (ROWS + 127) / 128, 1);
            hipLaunchKernelGGL(gemm_mfma_kernel, grid, dim3(256), 0, stream,
                               (const void*)yout_f, (const void*)yout_b, DI_,
                               out_proj + (size_t)i * E_ * DI_, nullptr, nullptr, hidden,
                               nullptr, E_, ROWS, E_, DI_, 1);
        }
        if (i == 5 || i == 11 || i == 17 || i == 23) {
            hipLaunchKernelGGL(feat_kernel, dim3(FEAT / 256), dim3(256), 0, stream, hidden,
                               out + OUT0 + (size_t)fidx * FEAT);
            ++fidx;
        }
    }
    hipLaunchKernelGGL(resid_ln_kernel, dim3(ROWS / 4), dim3(256), 0, stream, residual, hidden,
                       normf_w, normf_b, out, ROWS);
}

// Round 11
// 9330.456 us; speedup vs baseline: 1.3240x; 1.2017x over previous
//
#include <hip/hip_runtime.h>
#include <math.h>

#define B_   32
#define L_   197
#define E_   384
#define DI_  768
#define DS_  16
#define DR_  24
#define NP_  196
#define ROWS (B_ * L_)         // 6304
#define OUT0 (ROWS * E_)       // 2420736
#define FEAT (B_ * E_ * NP_)   // 2408448

typedef __attribute__((ext_vector_type(8))) short bf16x8;
typedef __attribute__((ext_vector_type(4))) float f32x4;

__device__ __forceinline__ float silu_f(float x) { return x / (1.f + __expf(-x)); }

__device__ __forceinline__ unsigned short f2bf(float x) {
    unsigned int u = __float_as_uint(x);
    u += 0x7fffu + ((u >> 16) & 1u);
    return (unsigned short)(u >> 16);
}
__device__ __forceinline__ float bf2f(unsigned short u) {
    return __uint_as_float((unsigned int)u << 16);
}
__device__ __forceinline__ float bflo(unsigned int u) { return __uint_as_float(u << 16); }
__device__ __forceinline__ float bfhi(unsigned int u) {
    return __uint_as_float(u & 0xffff0000u);
}

// ---------------- im2col for patch embedding ----------------
__global__ __launch_bounds__(256) void im2col_kernel(const float* __restrict__ x,
                                                     float* __restrict__ xcol) {
    int idx = blockIdx.x * 256 + threadIdx.x;
    if (idx >= B_ * NP_ * 768) return;
    int k = idx % 768;
    int bp = idx / 768;
    int pi = bp % NP_, b = bp / NP_;
    int gi = pi / 14, gj = pi % 14;
    int c = k >> 8, r = k & 255, p = r >> 4, q = r & 15;
    xcol[idx] = x[((size_t)(b * 3 + c) * 224 + gi * 16 + p) * 224 + gj * 16 + q];
}

// ---------------- assemble hidden: patches + cls + pos ----------------
__global__ __launch_bounds__(256) void assemble_kernel(const float* __restrict__ patchbuf,
                                                       const float* __restrict__ cls,
                                                       const float* __restrict__ pos,
                                                       float* __restrict__ hidden) {
    int idx = blockIdx.x * 256 + threadIdx.x;
    if (idx >= ROWS * E_) return;
    int e = idx % E_;
    int bt = idx / E_;
    int tok = bt % L_, b = bt / L_;
    float v;
    if (tok == 98) v = cls[e];
    else {
        int pi = tok < 98 ? tok : tok - 1;
        v = patchbuf[(size_t)(b * NP_ + pi) * E_ + e];
    }
    hidden[idx] = v + pos[tok * E_ + e];
}

// ---------------- bf16 MFMA GEMM ----------------
// C = A(MxK)*W(NxK fp32)^T + bias.  K % 32 == 0 required.
// amode 0: A fp32 (A0v/A1v by blockIdx.z)
// amode 4: A bf16 (A0v/A1v by blockIdx.z)
// amode 1: A = 0.5*(A0v + A1v), both bf16 (dir-average fold)
__global__ __launch_bounds__(256) void gemm_mfma_kernel(
    const void* A0v, const void* A1v, int lda,
    const float* __restrict__ W0, const float* __restrict__ W1,
    const float* __restrict__ bias,
    float* C0, float* C1, int ldc, int M, int N, int K, int amode) {
    __shared__ unsigned short As[128][32];
    __shared__ unsigned short Ws[128][32];
    const int tid = threadIdx.x;
    const int wave = tid >> 6, lane = tid & 63;
    const int wr = wave >> 1, wc = wave & 1;
    const int bm = blockIdx.y * 128, bn = blockIdx.x * 128;
    const int fr = lane & 15, fq = lane >> 4;
    const int r = tid >> 3, c4 = tid & 7;
    const float* W = blockIdx.z ? W1 : W0;
    float* C = blockIdx.z ? C1 : C0;
    const void* Av = blockIdx.z ? A1v : A0v;
    f32x4 acc[4][4] = {};

    for (int k0 = 0; k0 < K; k0 += 32) {
        __syncthreads();
        const int kbase = k0 + c4 * 4;
#pragma unroll
        for (int it = 0; it < 4; ++it) {
            int row = it * 32 + r;
            int gm = bm + row;
            ushort4 ua = {0, 0, 0, 0};
            if (gm < M) {
                if (amode == 0) {
                    const float* A = (const float*)Av;
                    float4 va = *(const float4*)&A[(size_t)gm * lda + kbase];
                    ua.x = f2bf(va.x); ua.y = f2bf(va.y);
                    ua.z = f2bf(va.z); ua.w = f2bf(va.w);
                } else if (amode == 1) {
                    const unsigned short* Af = (const unsigned short*)A0v;
                    const unsigned short* Ab = (const unsigned short*)A1v;
                    size_t off = (size_t)gm * lda + kbase;
                    ushort4 uf = *(const ushort4*)&Af[off];
                    ushort4 ub = *(const ushort4*)&Ab[off];
                    ua.x = f2bf((bf2f(uf.x) + bf2f(ub.x)) * 0.5f);
                    ua.y = f2bf((bf2f(uf.y) + bf2f(ub.y)) * 0.5f);
                    ua.z = f2bf((bf2f(uf.z) + bf2f(ub.z)) * 0.5f);
                    ua.w = f2bf((bf2f(uf.w) + bf2f(ub.w)) * 0.5f);
                } else {
                    const unsigned short* A = (const unsigned short*)Av;
                    ua = *(const ushort4*)&A[(size_t)gm * lda + kbase];
                }
            }
            *(ushort4*)&As[row][c4 * 4] = ua;
            int gn = bn + row;
            ushort4 uw = {0, 0, 0, 0};
            if (gn < N) {
                float4 vw = *(const float4*)&W[(size_t)gn * K + kbase];
                uw.x = f2bf(vw.x); uw.y = f2bf(vw.y);
                uw.z = f2bf(vw.z); uw.w = f2bf(vw.w);
            }
            *(ushort4*)&Ws[row][c4 * 4] = uw;
        }
        __syncthreads();
        bf16x8 af[4], bfr[4];
#pragma unroll
        for (int i = 0; i < 4; ++i) {
            af[i]  = *(const bf16x8*)&As[wr * 64 + i * 16 + fr][fq * 8];
            bfr[i] = *(const bf16x8*)&Ws[wc * 64 + i * 16 + fr][fq * 8];
        }
#pragma unroll
        for (int i = 0; i < 4; ++i)
#pragma unroll
            for (int j = 0; j < 4; ++j)
                acc[i][j] =
                    __builtin_amdgcn_mfma_f32_16x16x32_bf16(af[i], bfr[j], acc[i][j], 0, 0, 0);
    }

#pragma unroll
    for (int j = 0; j < 4; ++j) {
        int n = bn + wc * 64 + j * 16 + fr;
        if (n >= N) continue;
        float bv = bias ? bias[n] : 0.f;
#pragma unroll
        for (int i = 0; i < 4; ++i) {
#pragma unroll
            for (int rr = 0; rr < 4; ++rr) {
                int m = bm + wr * 64 + i * 16 + fq * 4 + rr;
                if (m < M) C[(size_t)m * ldc + n] = acc[i][j][rr] + bv;
            }
        }
    }
}

// ---------------- fused residual += hidden ; out = LayerNorm(residual) ----------------
__global__ __launch_bounds__(256) void resid_ln_kernel(float* __restrict__ residual,
                                                       const float* __restrict__ hidden,
                                                       const float* __restrict__ w,
                                                       const float* __restrict__ b,
                                                       float* __restrict__ out,
                                                       int nrows) {
    int row = blockIdx.x * 4 + (threadIdx.x >> 6);
    int lane = threadIdx.x & 63;
    if (row >= nrows) return;
    const float* rp = residual + (size_t)row * E_;
    const float* hp = hidden + (size_t)row * E_;
    float v[6];
    float sum = 0.f;
#pragma unroll
    for (int i = 0; i < 6; ++i) {
        int c = lane + i * 64;
        float x = rp[c] + hp[c];
        v[i] = x;
        sum += x;
    }
#pragma unroll
    for (int o = 32; o; o >>= 1) sum += __shfl_xor(sum, o);
    float mean = sum * (1.f / E_);
    float vs = 0.f;
#pragma unroll
    for (int i = 0; i < 6; ++i) {
        float d = v[i] - mean;
        vs += d * d;
    }
#pragma unroll
    for (int o = 32; o; o >>= 1) vs += __shfl_xor(vs, o);
    float rstd = rsqrtf(vs * (1.f / E_) + 1e-5f);
#pragma unroll
    for (int i = 0; i < 6; ++i) {
        int c = lane + i * 64;
        residual[(size_t)row * E_ + c] = v[i];
        out[(size_t)row * E_ + c] = (v[i] - mean) * rstd * w[c] + b[c];
    }
}

// ------- causal conv1d + SiLU -> bf16, both dirs; dir0 also emits silu(z) bf16 --------
__global__ __launch_bounds__(256) void conv_silu2b_kernel(const float* __restrict__ xz,
                                                          const float* __restrict__ cw_f,
                                                          const float* __restrict__ cb_f,
                                                          const float* __restrict__ cw_b,
                                                          const float* __restrict__ cb_b,
                                                          unsigned short* __restrict__ xc_f,
                                                          unsigned short* __restrict__ xc_b,
                                                          unsigned short* __restrict__ zsilu) {
    int rev = blockIdx.y;
    const float* cw = rev ? cw_b : cw_f;
    const float* cb = rev ? cb_b : cb_f;
    unsigned short* xc = rev ? xc_b : xc_f;
    int idx = blockIdx.x * 256 + threadIdx.x;
    if (idx >= B_ * L_ * DI_) return;
    int d = idx % DI_;
    int bt = idx / DI_;
    int t = bt % L_, b = bt / L_;
    float acc = cb[d];
#pragma unroll
    for (int k = 0; k < 4; ++k) {
        int tt = t - 3 + k;
        if (tt >= 0) {
            int pos = rev ? (L_ - 1 - tt) : tt;
            acc += cw[d * 4 + k] * xz[(size_t)(b * L_ + pos) * (2 * DI_) + d];
        }
    }
    xc[idx] = f2bf(silu_f(acc));
    if (rev == 0) {
        float zv = xz[(size_t)bt * (2 * DI_) + DI_ + d];
        zsilu[idx] = f2bf(silu_f(zv));
    }
}

// ---------------- chunk-parallel SSM scan, 8 d's/block, XCD-affinity swizzle ----------
// Paired LDS reads (float2/uint) + batched 16-t transpose-reduce (15 shfl per 16 t).
__global__ __launch_bounds__(512, 8) void scan8_kernel(
    const unsigned short* __restrict__ xcl_f, const unsigned short* __restrict__ xcl_b,
    const float* __restrict__ xdbl_f, const float* __restrict__ xdbl_b,
    const unsigned short* __restrict__ zsilu,
    const float* __restrict__ dtw_f, const float* __restrict__ dtw_b,
    const float* __restrict__ dtb_f, const float* __restrict__ dtb_b,
    const float* __restrict__ Alog_f, const float* __restrict__ Alog_b,
    const float* __restrict__ Dv_f, const float* __restrict__ Dv_b,
    unsigned short* __restrict__ yout_f, unsigned short* __restrict__ yout_b) {
    // swizzled decode: bid%8 == pair%8 -> same XCD serves one (b,dir)'s blocks
    int bid = blockIdx.x;
    int xcd = bid & 7;
    int rdec = bid >> 3;
    int dg = rdec % 96;
    int ph = rdec / 96;
    int p = ph * 8 + xcd;
    const int b = p >> 1, dir = p & 1;
    const int d0 = dg * 8;

    const unsigned short* xcl = dir ? xcl_b : xcl_f;
    const float* xdbl = dir ? xdbl_b : xdbl_f;
    const float* dtw  = dir ? dtw_b : dtw_f;
    const float* dtbp = dir ? dtb_b : dtb_f;
    const float* Alog = dir ? Alog_b : Alog_f;
    const float* Dv   = dir ? Dv_b : Dv_f;
    unsigned short* yout = dir ? yout_b : yout_f;
    const int tid = threadIdx.x;

    __shared__ float dt_s[8][200];                        // f32: exp-sensitive
    __shared__ unsigned short g_s[8][200];
    __shared__ unsigned short u_s[8][200];
    __shared__ unsigned short z_s[8][200];
    __shared__ unsigned short y_s[8][200];
    __shared__ unsigned short B_s[16][212];               // n-major, bank-free
    __shared__ unsigned short C_s[16][212];
    __shared__ float Ps[8][4][16], Ss[8][4][16], hin[8][4][16];
    __shared__ float dtw_s[8][24];

    if (tid < 192) dtw_s[tid / 24][tid % 24] = dtw[(d0 + tid / 24) * 24 + tid % 24];
    __syncthreads();

    // stage B, C into n-major bf16 (coalesced xdbl row reads)
    for (int e = tid; e < 3200; e += 512) {
        int t = e >> 4, nn = e & 15;
        float Bv = 0.f, Cv = 0.f;
        if (t < L_) {
            const float* xr = &xdbl[(size_t)(b * L_ + t) * 56];
            Bv = xr[24 + nn];
            Cv = xr[40 + nn];
        }
        B_s[nn][t] = f2bf(Bv);
        C_s[nn][t] = f2bf(Cv);
    }
    // stage dt (f32), g=dt*u (bf16), u, z — paired t's per thread
    for (int e = tid; e < 800; e += 512) {
        int dd = e & 7, q = e >> 3;             // q = 0..99 -> t = 2q, 2q+1
        float dtv[2], uv[2], zv[2];
#pragma unroll
        for (int h = 0; h < 2; ++h) {
            int t = 2 * q + h;
            dtv[h] = 0.f; uv[h] = 0.f; zv[h] = 0.f;
            if (t < L_) {
                size_t row = (size_t)(b * L_ + t);
                int pos = dir ? (L_ - 1 - t) : t;
                uv[h] = bf2f(xcl[row * DI_ + d0 + dd]);
                zv[h] = bf2f(zsilu[(size_t)(b * L_ + pos) * DI_ + d0 + dd]);
                const float* xr = &xdbl[row * 56];
                float acc = dtbp[d0 + dd];
#pragma unroll
                for (int rr = 0; rr < 24; ++rr) acc += xr[rr] * dtw_s[dd][rr];
                dtv[h] = (acc > 20.f) ? acc : log1pf(__expf(acc));
            }
        }
        *(float2*)&dt_s[dd][2 * q] = make_float2(dtv[0], dtv[1]);
        ushort2 ug = {f2bf(dtv[0] * uv[0]), f2bf(dtv[1] * uv[1])};
        ushort2 uu = {f2bf(uv[0]), f2bf(uv[1])};
        ushort2 uz = {f2bf(zv[0]), f2bf(zv[1])};
        *(ushort2*)&g_s[dd][2 * q] = ug;
        *(ushort2*)&u_s[dd][2 * q] = uu;
        *(ushort2*)&z_s[dd][2 * q] = uz;
    }
    __syncthreads();

    const int dd = tid >> 6;           // wave = d within group
    const int tt = (tid >> 4) & 3;     // chunk
    const int n = tid & 15;            // state
    const float An = -__expf(Alog[(d0 + dd) * DS_ + n]);
    const int t0 = tt * 50;            // even -> paired reads aligned

    const float* dtp = &dt_s[dd][t0];
    const unsigned short* gp = &g_s[dd][t0];
    const unsigned short* Bp = &B_s[n][t0];
    const unsigned short* Cp = &C_s[n][t0];

    // pass 1: chunk (P,S), paired
    float P = 1.f, S = 0.f;
#pragma unroll 5
    for (int i = 0; i < 50; i += 2) {
        float2 dt2 = *(const float2*)&dtp[i];
        unsigned int g2 = *(const unsigned int*)&gp[i];
        unsigned int B2 = *(const unsigned int*)&Bp[i];
        float a0 = __expf(dt2.x * An);
        float a1 = __expf(dt2.y * An);
        S = S * a0 + bflo(g2) * bflo(B2);
        S = S * a1 + bfhi(g2) * bfhi(B2);
        P *= a0 * a1;
    }
    Ps[dd][tt][n] = P;
    Ss[dd][tt][n] = S;
    __syncthreads();
    if (tid < 128) {
        int cdd = tid >> 4, cn = tid & 15;
        float h = 0.f;
#pragma unroll
        for (int c = 0; c < 4; ++c) {
            hin[cdd][c][cn] = h;
            h = Ps[cdd][c][cn] * h + Ss[cdd][c][cn];
        }
    }
    __syncthreads();

    // pass 2: replay, 3 groups of 16 t + 2-t tail; batched transpose-reduce per group
    float h = hin[dd][tt][n];
    const float Dval = Dv[d0 + dd];
    const bool up8 = (n & 8) != 0;
    const bool up4 = (n & 4) != 0;
    const bool up2 = (n & 2) != 0;
    const bool up1 = (n & 1) != 0;
#pragma unroll
    for (int grp = 0; grp < 3; ++grp) {
        const int base = grp * 16;
        float pv[16];
#pragma unroll
        for (int i = 0; i < 16; i += 2) {
            float2 dt2 = *(const float2*)&dtp[base + i];
            unsigned int g2 = *(const unsigned int*)&gp[base + i];
            unsigned int B2 = *(const unsigned int*)&Bp[base + i];
            unsigned int C2 = *(const unsigned int*)&Cp[base + i];
            float a0 = __expf(dt2.x * An);
            h = a0 * h + bflo(g2) * bflo(B2);
            pv[i] = h * bflo(C2);
            float a1 = __expf(dt2.y * An);
            h = a1 * h + bfhi(g2) * bfhi(B2);
            pv[i + 1] = h * bfhi(C2);
        }
        // butterfly transpose-reduce: lane n ends with full n-sum for t = t0+base+n
#pragma unroll
        for (int j = 0; j < 8; ++j) {
            float send = up8 ? pv[j] : pv[j + 8];
            float recv = __shfl_xor(send, 8);
            pv[j] = (up8 ? pv[j + 8] : pv[j]) + recv;
        }
#pragma unroll
        for (int j = 0; j < 4; ++j) {
            float send = up4 ? pv[j] : pv[j + 4];
            float recv = __shfl_xor(send, 4);
            pv[j] = (up4 ? pv[j + 4] : pv[j]) + recv;
        }
#pragma unroll
        for (int j = 0; j < 2; ++j) {
            float send = up2 ? pv[j] : pv[j + 2];
            float recv = __shfl_xor(send, 2);
            pv[j] = (up2 ? pv[j + 2] : pv[j]) + recv;
        }
        {
            float send = up1 ? pv[0] : pv[1];
            float recv = __shfl_xor(send, 1);
            pv[0] = (up1 ? pv[1] : pv[0]) + recv;
        }
        int t = t0 + base + n;
        if (t < L_) {
            float yv = (pv[0] + bf2f(u_s[dd][t]) * Dval) * bf2f(z_s[dd][t]);
            y_s[dd][t] = f2bf(yv);
        }
    }
    // tail: t = t0+48, t0+49
#pragma unroll
    for (int i = 48; i < 50; ++i) {
        float a = __expf(dtp[i] * An);
        h = a * h + bf2f(gp[i]) * bf2f(Bp[i]);
        float y = h * bf2f(Cp[i]);
        y += __shfl_xor(y, 1);
        y += __shfl_xor(y, 2);
        y += __shfl_xor(y, 4);
        y += __shfl_xor(y, 8);
        int t = t0 + i;
        if (n == 0 && t < L_)
            y_s[dd][t] = f2bf((y + bf2f(u_s[dd][t]) * Dval) * bf2f(z_s[dd][t]));
    }
    __syncthreads();
    // coalesced row-major writeout (y for output position pos lives at scan index t)
    for (int e = tid; e < 1600; e += 512) {
        int dd2 = e & 7, t = e >> 3;
        if (t < L_) {
            int pos = dir ? (L_ - 1 - t) : t;
            yout[(size_t)(b * L_ + pos) * DI_ + d0 + dd2] = y_s[dd2][t];
        }
    }
}

// ---------------- feature extraction ----------------
__global__ __launch_bounds__(256) void feat_kernel(const float* __restrict__ hidden,
                                                   float* __restrict__ out) {
    int idx = blockIdx.x * 256 + threadIdx.x;
    if (idx >= FEAT) return;
    int p = idx % NP_;
    int be = idx / NP_;
    int e = be % E_, b = be / E_;
    int tok = p < 98 ? p : p + 1;
    out[idx] = hidden[(size_t)(b * L_ + tok) * E_ + e];
}

static inline void launch_gemm_f32(const float* A, int lda, const float* W, const float* bias,
                                   float* C, int ldc, int M, int N, int K,
                                   hipStream_t stream) {
    dim3 grid((N + 127) / 128, (M + 127) / 128, 1);
    hipLaunchKernelGGL(gemm_mfma_kernel, grid, dim3(256), 0, stream, (const void*)A, nullptr,
                       lda, W, nullptr, bias, C, nullptr, ldc, M, N, K, 0);
}

extern "C" void kernel_launch(void* const* d_in, const int* in_sizes, int n_in, void* d_out,
                              int out_size, void* d_ws, size_t ws_size, hipStream_t stream) {
    const float* x        = (const float*)d_in[0];
    const float* patch_w  = (const float*)d_in[1];
    const float* patch_b  = (const float*)d_in[2];
    const float* cls_tok  = (const float*)d_in[3];
    const float* pos_emb  = (const float*)d_in[4];
    const float* norm_w   = (const float*)d_in[5];
    const float* norm_b   = (const float*)d_in[6];
    const float* in_proj  = (const float*)d_in[7];
    const float* conv_w   = (const float*)d_in[8];
    const float* conv_b   = (const float*)d_in[9];
    const float* xproj_w  = (const float*)d_in[10];
    const float* dtproj_w = (const float*)d_in[11];
    const float* dtproj_b = (const float*)d_in[12];
    const float* A_log    = (const float*)d_in[13];
    const float* D_param  = (const float*)d_in[14];
    const float* conv_wb  = (const float*)d_in[15];
    const float* conv_bb  = (const float*)d_in[16];
    const float* xproj_wb = (const float*)d_in[17];
    const float* dtproj_wb= (const float*)d_in[18];
    const float* dtproj_bb= (const float*)d_in[19];
    const float* A_logb   = (const float*)d_in[20];
    const float* D_paramb = (const float*)d_in[21];
    const float* out_proj = (const float*)d_in[22];
    const float* normf_w  = (const float*)d_in[23];
    const float* normf_b  = (const float*)d_in[24];
    float* out = (float*)d_out;

    float* ws       = (float*)d_ws;
    float* residual = ws;                                    // 2,420,736 f32
    float* hidden   = residual + OUT0;                       // 2,420,736 f32
    float* xz       = hidden + OUT0;                         // 9,682,944 f32
    unsigned short* xcl_f = (unsigned short*)(xz + (size_t)ROWS * 1536);  // ROWS*768 u16
    unsigned short* xcl_b = xcl_f + (size_t)ROWS * DI_;
    unsigned short* zsilu = xcl_b + (size_t)ROWS * DI_;
    float* xdbl_f   = (float*)(zsilu + (size_t)ROWS * DI_);  // 353,024 f32
    float* xdbl_b   = xdbl_f + (size_t)ROWS * 56;
    unsigned short* yout_f = (unsigned short*)(xdbl_b + (size_t)ROWS * 56);
    unsigned short* yout_b = yout_f + (size_t)ROWS * DI_;
    // overlays (timeline-disjoint)
    float* hn       = (float*)yout_f;  // alive LN -> in_proj; yout alive scan -> out_proj
    float* xcol     = xz;              // pre-layer only
    float* patchbuf = (float*)yout_f;  // pre-layer only

    hipMemsetAsync(residual, 0, (size_t)OUT0 * sizeof(float), stream);

    // patch embedding
    hipLaunchKernelGGL(im2col_kernel, dim3((B_ * NP_ * 768 + 255) / 256), dim3(256), 0, stream,
                       x, xcol);
    launch_gemm_f32(xcol, 768, patch_w, patch_b, patchbuf, E_, B_ * NP_, E_, 768, stream);
    hipLaunchKernelGGL(assemble_kernel, dim3((ROWS * E_ + 255) / 256), dim3(256), 0, stream,
                       patchbuf, cls_tok, pos_emb, hidden);

    int fidx = 0;
    for (int i = 0; i < 24; ++i) {
        hipLaunchKernelGGL(resid_ln_kernel, dim3(ROWS / 4), dim3(256), 0, stream, residual,
                           hidden, norm_w + i * E_, norm_b + i * E_, hn, ROWS);
        launch_gemm_f32(hn, E_, in_proj + (size_t)i * 1536 * E_, nullptr, xz, 1536, ROWS, 1536,
                        E_, stream);
        hipLaunchKernelGGL(conv_silu2b_kernel, dim3(B_ * L_ * DI_ / 256, 2), dim3(256), 0,
                           stream, xz, conv_w + (size_t)i * DI_ * 4, conv_b + (size_t)i * DI_,
                           conv_wb + (size_t)i * DI_ * 4, conv_bb + (size_t)i * DI_, xcl_f,
                           xcl_b, zsilu);
        // batched x_proj GEMM over both directions (bf16 A)
        {
            dim3 grid(1, (ROWS + 127) / 128, 2);
            hipLaunchKernelGGL(gemm_mfma_kernel, grid, dim3(256), 0, stream,
                               (const void*)xcl_f, (const void*)xcl_b, DI_,
                               xproj_w + (size_t)i * 56 * DI_, xproj_wb + (size_t)i * 56 * DI_,
                               nullptr, xdbl_f, xdbl_b, 56, ROWS, 56, DI_, 4);
        }
        hipLaunchKernelGGL(scan8_kernel, dim3(6144), dim3(512), 0, stream, xcl_f, xcl_b,
                           xdbl_f, xdbl_b, zsilu, dtproj_w + (size_t)i * DI_ * DR_,
                           dtproj_wb + (size_t)i * DI_ * DR_, dtproj_b + (size_t)i * DI_,
                           dtproj_bb + (size_t)i * DI_, A_log + (size_t)i * DI_ * DS_,
                           A_logb + (size_t)i * DI_ * DS_, D_param + (size_t)i * DI_,
                           D_paramb + (size_t)i * DI_, yout_f, yout_b);
        // out_proj: A = 0.5*(yout_f + yout_b), both bf16 row-major
        {
            dim3 grid((E_ + 127) / 128, (ROWS + 127) / 128, 1);
            hipLaunchKernelGGL(gemm_mfma_kernel, grid, dim3(256), 0, stream,
                               (const void*)yout_f, (const void*)yout_b, DI_,
                               out_proj + (size_t)i * E_ * DI_, nullptr, nullptr, hidden,
                               nullptr, E_, ROWS, E_, DI_, 1);
        }
        if (i == 5 || i == 11 || i == 17 || i == 23) {
            hipLaunchKernelGGL(feat_kernel, dim3(FEAT / 256), dim3(256), 0, stream, hidden,
                               out + OUT0 + (size_t)fidx * FEAT);
            ++fidx;
        }
    }
    hipLaunchKernelGGL(resid_ln_kernel, dim3(ROWS / 4), dim3(256), 0, stream, residual, hidden,
                       normf_w, normf_b, out, ROWS);
}